// Round 15
// baseline (114.086 us; speedup 1.0000x reference)
//
#include <hip/hip_runtime.h>
#include <hip/hip_bf16.h>

#define B_DIM 256
#define I_DIM 128
#define O_DIM 128
#define H_DIM 32
#define F_DIM 7
#define ICHUNK 4
#define NCHUNK (I_DIM / ICHUNK)   // 32

typedef __attribute__((ext_vector_type(8))) short short8;   // 8 bf16 (4 VGPRs)
typedef __attribute__((ext_vector_type(4))) float float4v;  // MFMA C/D

// Async global->LDS DMA, 16B/lane, wave-uniform LDS base + lane*16 (R6-proven).
#define GLOAD_LDS16(g, l) __builtin_amdgcn_global_load_lds( \
    (const __attribute__((address_space(1))) void*)(g),     \
    (__attribute__((address_space(3))) void*)(l), 16, 0, 0)

__device__ inline short bf16s(float v) {
    union { __hip_bfloat16 h; short s; } u;
    u.h = __float2bfloat16(v);
    return u.s;
}

// Pre-kernel: bf16-packed A-rows featw[i][b][8] = {x,sin x,sin 2x,sin 4x,
// cos x,cos 2x,cos 4x,0}. 1 MB, written fully every launch (re-poison safe).
// Kills the 128x redundant per-o-block trig of R11-R14 (4.2M -> 32k evals).
__global__ void feat_kernel(const float* __restrict__ x, short* __restrict__ featw) {
    const int i = blockIdx.x;
    const int b = threadIdx.x;
    float xv = x[(size_t)b * I_DIM + i];
    float s1 = __sinf(xv), c1 = __cosf(xv);
    float s2 = 2.f * s1 * c1, c2 = 1.f - 2.f * s1 * s1;
    float s4 = 2.f * s2 * c2, c4 = 1.f - 2.f * s2 * s2;
    short8 a;
    a[0] = bf16s(xv); a[1] = bf16s(s1); a[2] = bf16s(s2); a[3] = bf16s(s4);
    a[4] = bf16s(c1); a[5] = bf16s(c2); a[6] = bf16s(c4); a[7] = 0;
    *reinterpret_cast<short8*>(featw + ((size_t)i * B_DIM + b) * 8) = a;
}

// R15 = R14 with staging offloaded (loop body byte-identical).
// R14 post-mortem: occupancy 30->46% moved nothing (R13 4blk/CU == R14
// 8blk/CU == ~42us) -> remaining cost is staging busy (~2.7us redundant trig)
// and per-block staging latency exposed at the barrier. R15:
//  - stage A = 16 KB contiguous copy from featw via global_load_lds dwordx4
//    (zero VALU, async; barrier's vmcnt drain completes it — R6-proven).
//  - stage B = coalesced: per-(i,o) W1 slice is 224 CONTIGUOUS floats;
//    e-loop reads stride-1 (was 128 threads x 7 scattered dwords), cvt,
//    ds_write_b16 into the [h][8] bf16 layout.
//
// REGISTER-PRESSURE LAW (R2/R4/R5): __launch_bounds__(256,w) hard-caps VGPR
// at 256/w; allocator SPILLS to meet it. (256,4)=cap 64 proven for this body
// (R12/R14: VGPR 40, zero scratch). il-loop rolled (unroll 1) per R4.
template <bool USE_WS>
__global__ __launch_bounds__(256, 4)
void fcnkan_mfma(const float* __restrict__ x,
                 const float* __restrict__ W1,
                 const float* __restrict__ W2,
                 const float* __restrict__ B1,
                 const float* __restrict__ B2,
                 const short* __restrict__ featw,
                 float* __restrict__ ws,
                 float* __restrict__ out) {
    __shared__ __align__(16) short feat_s[ICHUNK * B_DIM * 8];   // 16 KB
    __shared__ __align__(16) short w1_s[ICHUNK * H_DIM * 8];     // 2 KB
    __shared__ float b1_s[ICHUNK * H_DIM];                       // 0.5 KB
    __shared__ float w2_s[ICHUNK * H_DIM];                       // 0.5 KB

    const int tid  = threadIdx.x;
    const int o    = blockIdx.x;
    const int ic0  = blockIdx.y * ICHUNK;
    const int w    = tid >> 6;       // wave: b-range [w*64, w*64+64)
    const int lane = tid & 63;
    const int m    = lane & 15;      // row/col within 16x16 tile
    const int q    = lane >> 4;      // quad

    const short8 zero8 = {};

    // ---- stage A ----
    if (USE_WS) {
        // contiguous 16 KB DMA: featw[ic0..ic0+3][b][8] -> feat_s, same layout
        const char* src = reinterpret_cast<const char*>(featw + (size_t)ic0 * B_DIM * 8);
        char* dst = reinterpret_cast<char*>(feat_s);
        #pragma unroll
        for (int t = 0; t < 4; ++t) {
            int c = w * 4 + t;                       // 1 KB chunk per wave-call
            GLOAD_LDS16(src + c * 1024 + lane * 16, dst + c * 1024 + lane * 16);
        }
    } else {
        const float4* xp = reinterpret_cast<const float4*>(x + (size_t)tid * I_DIM + ic0);
        float4 x0 = xp[0];
        float xr[4] = {x0.x, x0.y, x0.z, x0.w};
        #pragma unroll
        for (int il = 0; il < ICHUNK; ++il) {
            float xv = xr[il];
            float s1 = __sinf(xv), c1 = __cosf(xv);
            float s2 = 2.f * s1 * c1, c2 = 1.f - 2.f * s1 * s1;
            float s4 = 2.f * s2 * c2, c4 = 1.f - 2.f * s2 * s2;
            short8 a;
            a[0] = bf16s(xv); a[1] = bf16s(s1); a[2] = bf16s(s2); a[3] = bf16s(s4);
            a[4] = bf16s(c1); a[5] = bf16s(c2); a[6] = bf16s(c4); a[7] = 0;
            *reinterpret_cast<short8*>(feat_s + (il * B_DIM + tid) * 8) = a;
        }
    }

    // ---- stage B: coalesced W1 (224 contiguous floats per il), cvt to bf16 ----
    for (int e = tid; e < ICHUNK * H_DIM * F_DIM; e += 256) {
        int il = e / (H_DIM * F_DIM);
        int r  = e - il * (H_DIM * F_DIM);          // 0..223, stride-1 loads
        float v = W1[((size_t)(ic0 + il) * O_DIM + o) * (H_DIM * F_DIM) + r];
        int h = r / F_DIM, f = r - h * F_DIM;
        w1_s[(il * H_DIM + h) * 8 + f] = bf16s(v);
    }
    if (tid < ICHUNK * H_DIM) {
        w1_s[tid * 8 + 7] = 0;
        int il = tid >> 5, h = tid & 31;
        size_t iobase = (size_t)(ic0 + il) * O_DIM + o;
        b1_s[tid] = B1[iobase * H_DIM + h];
        w2_s[tid] = W2[iobase * H_DIM + h];
    }
    __syncthreads();   // drains staging writes + async feat DMA

    float acc[16];
    #pragma unroll
    for (int r = 0; r < 16; ++r) acc[r] = 0.f;

    #pragma unroll 1
    for (int il = 0; il < ICHUNK; ++il) {
        const short8* fS = reinterpret_cast<const short8*>(feat_s) + il * B_DIM;
        const short8* wS = reinterpret_cast<const short8*>(w1_s) + il * H_DIM;

        short8 afrag[4];
        #pragma unroll
        for (int t = 0; t < 4; ++t)
            afrag[t] = fS[w * 64 + t * 16 + m];          // ds_read_b128

        short8 bfrag[2];
        float  b1v[2], w2v[2];
        #pragma unroll
        for (int nt = 0; nt < 2; ++nt) {
            int h = nt * 16 + m;
            short8 b = wS[h];                            // ds_read_b128
            bfrag[nt] = (q == 0) ? b : zero8;            // only B quad-zeroed
            b1v[nt] = b1_s[il * H_DIM + h];
            w2v[nt] = w2_s[il * H_DIM + h];
        }

        #pragma unroll
        for (int nt = 0; nt < 2; ++nt) {
            float4v c0 = {b1v[nt], b1v[nt], b1v[nt], b1v[nt]};
            #pragma unroll
            for (int t = 0; t < 4; ++t) {
                float4v z = __builtin_amdgcn_mfma_f32_16x16x32_bf16(
                    afrag[t], bfrag[nt], c0, 0, 0, 0);
                #pragma unroll
                for (int r = 0; r < 4; ++r) {
                    float zz = z[r];
                    float sg = __builtin_amdgcn_rcpf(1.f + __expf(-zz));
                    acc[t * 4 + r] = fmaf(zz * sg, w2v[nt], acc[t * 4 + r]);
                }
            }
        }
    }

    // ---- h-sum: butterfly over the 16 lanes of each quad-group ----
    #pragma unroll
    for (int r = 0; r < 16; ++r) {
        float v = acc[r];
        v += __shfl_xor(v, 1, 64);
        v += __shfl_xor(v, 2, 64);
        v += __shfl_xor(v, 4, 64);
        v += __shfl_xor(v, 8, 64);
        acc[r] = v;
    }

    // per-chunk B2 contribution (uniform)
    float b2c = 0.f;
    #pragma unroll
    for (int il = 0; il < ICHUNK; ++il) b2c += B2[(size_t)(ic0 + il) * O_DIM + o];

    if (m == 0) {
        if (USE_WS) {
            float* wsp = ws + ((size_t)blockIdx.y * O_DIM + o) * B_DIM;
            #pragma unroll
            for (int t = 0; t < 4; ++t)
                #pragma unroll
                for (int r = 0; r < 4; ++r)
                    wsp[w * 64 + t * 16 + q * 4 + r] = acc[t * 4 + r] + b2c;
        } else {
            #pragma unroll
            for (int t = 0; t < 4; ++t)
                #pragma unroll
                for (int r = 0; r < 4; ++r) {
                    int b = w * 64 + t * 16 + q * 4 + r;
                    atomicAdd(&out[(size_t)b * O_DIM + o], acc[t * 4 + r] + b2c);
                }
        }
    }
}

// Sum the NCHUNK partials per (o,b). Coalesced; 4 MB, L2-resident.
__global__ __launch_bounds__(256)
void reduce_kernel(const float* __restrict__ ws, float* __restrict__ out) {
    const int o = blockIdx.x;
    const int b = threadIdx.x;
    float s = 0.f;
    #pragma unroll
    for (int c = 0; c < NCHUNK; ++c)
        s += ws[((size_t)c * O_DIM + o) * B_DIM + b];
    out[(size_t)b * O_DIM + o] = s;
}

extern "C" void kernel_launch(void* const* d_in, const int* in_sizes, int n_in,
                              void* d_out, int out_size, void* d_ws, size_t ws_size,
                              hipStream_t stream) {
    const float* x  = (const float*)d_in[0];
    const float* W1 = (const float*)d_in[1];
    const float* W2 = (const float*)d_in[2];
    const float* B1 = (const float*)d_in[3];
    const float* B2 = (const float*)d_in[4];
    float* out = (float*)d_out;

    const size_t feat_bytes = (size_t)I_DIM * B_DIM * 8 * sizeof(short);      // 1 MiB
    const size_t part_bytes = (size_t)NCHUNK * O_DIM * B_DIM * sizeof(float); // 4 MiB
    short* featw = (short*)d_ws;
    float* part  = (float*)((char*)d_ws + feat_bytes);

    dim3 grid(O_DIM, NCHUNK);
    if (ws_size >= feat_bytes + part_bytes) {   // launch-invariant -> graph-safe
        feat_kernel<<<I_DIM, B_DIM, 0, stream>>>(x, featw);
        fcnkan_mfma<true><<<grid, 256, 0, stream>>>(x, W1, W2, B1, B2, featw, part, out);
        reduce_kernel<<<O_DIM, B_DIM, 0, stream>>>(part, out);
    } else {
        hipMemsetAsync(out, 0, (size_t)out_size * sizeof(float), stream);
        fcnkan_mfma<false><<<grid, 256, 0, stream>>>(x, W1, W2, B1, B2, featw, part, out);
    }
}

// Round 16
// 108.442 us; speedup vs baseline: 1.0520x; 1.0520x over previous
//
#include <hip/hip_runtime.h>
#include <hip/hip_bf16.h>

#define B_DIM 256
#define I_DIM 128
#define O_DIM 128
#define H_DIM 32
#define F_DIM 7
#define ICHUNK 4
#define NCHUNK (I_DIM / ICHUNK)   // 32

typedef __attribute__((ext_vector_type(8))) short short8;   // 8 bf16 (4 VGPRs)
typedef __attribute__((ext_vector_type(4))) float float4v;  // MFMA C/D

__device__ inline short bf16s(float v) {
    union { __hip_bfloat16 h; short s; } u;
    u.h = __float2bfloat16(v);
    return u.s;
}

// VALU cross-lane add via DPP (no DS pipe, no lgkmcnt).
template <int CTRL>
__device__ __forceinline__ float dppadd(float v) {
    int s = __builtin_amdgcn_update_dpp(0, __builtin_bit_cast(int, v),
                                        CTRL, 0xF, 0xF, true);
    return v + __builtin_bit_cast(float, s);
}
// Full 16-lane (row) reduction: xor1, xor2, mirror-in-8 (pairs quads),
// mirror-in-16 (pairs half-rows). All lanes end with the total.
__device__ __forceinline__ float rowsum16(float v) {
    v = dppadd<0xB1>(v);    // quad_perm [1,0,3,2]
    v = dppadd<0x4E>(v);    // quad_perm [2,3,0,1]
    v = dppadd<0x141>(v);   // row_half_mirror
    v = dppadd<0x140>(v);   // row_mirror
    return v;
}

// R16 = R14 with the DS-pipe epilogue removed (two surgical changes).
// R15 post-mortem: staging offload regressed (div/mod VALU + 49k conflicts +
// extra dispatch); R14 staging restored. R13(4blk)==R14(8blk)==42us at 68%
// busy -> idle is occupancy-invariant == shared serial resource. DS-pipe
// accounting per CU: in-loop reads 9.2k + b1/w2 3k + staging 2.5k + epilogue
// __shfl_xor 2048 ds_swizzles ~12k = ~27k cyc/gen x 2 gens ~= 22us -- the
// epilogue butterfly is the largest removable item. R16:
//  1. h-sum via DPP adds on the VALU (rowsum16) -- zero DS ops in epilogue.
//  2. B-frag quad-zeroing via zero-row address select (1 cndmask/frag, the
//     48 q!=0 lanes broadcast-read one zero row -- free) instead of 8
//     register cndmasks.
//
// REGISTER-PRESSURE LAW (R2/R4/R5): __launch_bounds__(256,w) hard-caps VGPR
// at 256/w; allocator SPILLS to meet it. (256,4)=cap 64 proven for this body
// (R12/R14: VGPR 40, zero scratch). il-loop rolled (unroll 1) per R4.
template <bool USE_WS>
__global__ __launch_bounds__(256, 4)
void fcnkan_mfma(const float* __restrict__ x,
                 const float* __restrict__ W1,
                 const float* __restrict__ W2,
                 const float* __restrict__ B1,
                 const float* __restrict__ B2,
                 float* __restrict__ ws,
                 float* __restrict__ out) {
    __shared__ __align__(16) short feat_s[ICHUNK * B_DIM * 8];     // 16 KB
    __shared__ __align__(16) short w1_s[(ICHUNK * H_DIM + 1) * 8]; // +1 zero row
    __shared__ float b1_s[ICHUNK * H_DIM];
    __shared__ float w2_s[ICHUNK * H_DIM];

    const int tid  = threadIdx.x;
    const int o    = blockIdx.x;
    const int ic0  = blockIdx.y * ICHUNK;
    const int w    = tid >> 6;       // wave: b-range [w*64, w*64+64)
    const int lane = tid & 63;
    const int m    = lane & 15;      // row/col within 16x16 tile
    const int q    = lane >> 4;      // quad

    const short8 zero8 = {};
    const int ZROW = ICHUNK * H_DIM; // zero-row index in w1_s

    // ---- stage A: own x row (one float4), trig once per (b, il), bf16-pack ----
    {
        const float4* xp = reinterpret_cast<const float4*>(x + (size_t)tid * I_DIM + ic0);
        float4 x0 = xp[0];
        float xr[4] = {x0.x, x0.y, x0.z, x0.w};
        #pragma unroll
        for (int il = 0; il < ICHUNK; ++il) {
            float xv = xr[il];
            float s1 = __sinf(xv), c1 = __cosf(xv);
            float s2 = 2.f * s1 * c1, c2 = 1.f - 2.f * s1 * s1;
            float s4 = 2.f * s2 * c2, c4 = 1.f - 2.f * s2 * s2;
            short8 a;
            a[0] = bf16s(xv); a[1] = bf16s(s1); a[2] = bf16s(s2); a[3] = bf16s(s4);
            a[4] = bf16s(c1); a[5] = bf16s(c2); a[6] = bf16s(c4); a[7] = 0;
            *reinterpret_cast<short8*>(feat_s + (il * B_DIM + tid) * 8) = a;
        }
    }
    // ---- stage B: threads 0..127 <-> (il = tid>>5, h = tid&31), one W1 row ----
    if (tid < ICHUNK * H_DIM) {
        int il = tid >> 5, h = tid & 31;
        size_t iobase = (size_t)(ic0 + il) * O_DIM + o;
        const float* wr = W1 + iobase * (H_DIM * F_DIM) + h * F_DIM;
        short8 bfr;
        #pragma unroll
        for (int f = 0; f < F_DIM; ++f) bfr[f] = bf16s(wr[f]);
        bfr[7] = 0;
        *reinterpret_cast<short8*>(w1_s + tid * 8) = bfr;
        b1_s[tid] = B1[iobase * H_DIM + h];
        w2_s[tid] = W2[iobase * H_DIM + h];
    }
    if (tid == 128) *reinterpret_cast<short8*>(w1_s + ZROW * 8) = zero8;
    __syncthreads();

    float acc[16];
    #pragma unroll
    for (int r = 0; r < 16; ++r) acc[r] = 0.f;

    #pragma unroll 1
    for (int il = 0; il < ICHUNK; ++il) {
        const short8* fS   = reinterpret_cast<const short8*>(feat_s) + il * B_DIM;
        const short8* wAll = reinterpret_cast<const short8*>(w1_s);

        short8 afrag[4];
        #pragma unroll
        for (int t = 0; t < 4; ++t)
            afrag[t] = fS[w * 64 + t * 16 + m];          // ds_read_b128

        short8 bfrag[2];
        float  b1v[2], w2v[2];
        #pragma unroll
        for (int nt = 0; nt < 2; ++nt) {
            int h = nt * 16 + m;
            int idx = (q == 0) ? (il * H_DIM + h) : ZROW;  // addr select, not
            bfrag[nt] = wAll[idx];                         // 8 reg cndmasks
            b1v[nt] = b1_s[il * H_DIM + h];
            w2v[nt] = w2_s[il * H_DIM + h];
        }

        #pragma unroll
        for (int nt = 0; nt < 2; ++nt) {
            float4v c0 = {b1v[nt], b1v[nt], b1v[nt], b1v[nt]};
            #pragma unroll
            for (int t = 0; t < 4; ++t) {
                float4v z = __builtin_amdgcn_mfma_f32_16x16x32_bf16(
                    afrag[t], bfrag[nt], c0, 0, 0, 0);
                #pragma unroll
                for (int r = 0; r < 4; ++r) {
                    float zz = z[r];
                    float sg = __builtin_amdgcn_rcpf(1.f + __expf(-zz));
                    acc[t * 4 + r] = fmaf(zz * sg, w2v[nt], acc[t * 4 + r]);
                }
            }
        }
    }

    // ---- h-sum: DPP reduction over the 16 lanes of each quad-group (VALU) ----
    #pragma unroll
    for (int r = 0; r < 16; ++r) acc[r] = rowsum16(acc[r]);

    // per-chunk B2 contribution (uniform)
    float b2c = 0.f;
    #pragma unroll
    for (int il = 0; il < ICHUNK; ++il) b2c += B2[(size_t)(ic0 + il) * O_DIM + o];

    // lane m==0 of each quad-group stores its 16 rows (private ws slice,
    // written exactly once -> re-poison safe)
    if (m == 0) {
        if (USE_WS) {
            float* wsp = ws + ((size_t)blockIdx.y * O_DIM + o) * B_DIM;
            #pragma unroll
            for (int t = 0; t < 4; ++t)
                #pragma unroll
                for (int r = 0; r < 4; ++r)
                    wsp[w * 64 + t * 16 + q * 4 + r] = acc[t * 4 + r] + b2c;
        } else {
            #pragma unroll
            for (int t = 0; t < 4; ++t)
                #pragma unroll
                for (int r = 0; r < 4; ++r) {
                    int b = w * 64 + t * 16 + q * 4 + r;
                    atomicAdd(&out[(size_t)b * O_DIM + o], acc[t * 4 + r] + b2c);
                }
        }
    }
}

// Sum the NCHUNK partials per (o,b). Coalesced; 4 MB, L2-resident.
__global__ __launch_bounds__(256)
void reduce_kernel(const float* __restrict__ ws, float* __restrict__ out) {
    const int o = blockIdx.x;
    const int b = threadIdx.x;
    float s = 0.f;
    #pragma unroll
    for (int c = 0; c < NCHUNK; ++c)
        s += ws[((size_t)c * O_DIM + o) * B_DIM + b];
    out[(size_t)b * O_DIM + o] = s;
}

extern "C" void kernel_launch(void* const* d_in, const int* in_sizes, int n_in,
                              void* d_out, int out_size, void* d_ws, size_t ws_size,
                              hipStream_t stream) {
    const float* x  = (const float*)d_in[0];
    const float* W1 = (const float*)d_in[1];
    const float* W2 = (const float*)d_in[2];
    const float* B1 = (const float*)d_in[3];
    const float* B2 = (const float*)d_in[4];
    float* out = (float*)d_out;
    float* ws  = (float*)d_ws;

    const size_t ws_need = (size_t)NCHUNK * O_DIM * B_DIM * sizeof(float); // 4 MiB
    dim3 grid(O_DIM, NCHUNK);
    if (ws_size >= ws_need) {   // launch-invariant -> graph-safe
        fcnkan_mfma<true><<<grid, 256, 0, stream>>>(x, W1, W2, B1, B2, ws, out);
        reduce_kernel<<<O_DIM, B_DIM, 0, stream>>>(ws, out);
    } else {
        hipMemsetAsync(out, 0, (size_t)out_size * sizeof(float), stream);
        fcnkan_mfma<false><<<grid, 256, 0, stream>>>(x, W1, W2, B1, B2, ws, out);
    }
}